// Round 4
// baseline (701.241 us; speedup 1.0000x reference)
//
#include <hip/hip_runtime.h>
#include <stdint.h>

#define AS1 __attribute__((address_space(1)))
#define AS3 __attribute__((address_space(3)))

typedef __attribute__((ext_vector_type(8))) short bf16x8;
typedef __attribute__((ext_vector_type(4))) float f32x4;

// ================= Cl(4,1) ~= M4(C) isomorphism, built at compile time =================
// Generators (monomial 4x4 complex, entries i^ph):
//  E0=s1(x)I, E1=s2(x)I, E2=s3(x)s1, E3=s3(x)s2 (square +1); E4=i*s3(x)s3 (square -1).
// Blade A (5-bit mask) -> M_A = product of E_b over set bits, ascending. Each M_A is
// monomial: M_A[r, col[r]] = i^ph[r].

struct Mono { int col[4]; int ph[4]; };

constexpr Mono mono_mul(Mono A, Mono B) {
    Mono R{};
    for (int r = 0; r < 4; ++r) {
        int k = A.col[r];
        R.col[r] = B.col[k];
        R.ph[r] = (A.ph[r] + B.ph[k]) & 3;
    }
    return R;
}

constexpr Mono gen(int g) {
    Mono E{};
    for (int r = 0; r < 4; ++r) {
        int r1 = (r >> 1) & 1, r0 = r & 1;
        if (g == 0)      { E.col[r] = r ^ 2; E.ph[r] = 0; }
        else if (g == 1) { E.col[r] = r ^ 2; E.ph[r] = r1 ? 1 : 3; }
        else if (g == 2) { E.col[r] = r ^ 1; E.ph[r] = r1 ? 2 : 0; }
        else if (g == 3) { E.col[r] = r ^ 1; E.ph[r] = ((r1 ? 2 : 0) + (r0 ? 1 : 3)) & 3; }
        else             { E.col[r] = r;     E.ph[r] = (1 + (r1 ? 2 : 0) + (r0 ? 2 : 0)) & 3; }
    }
    return E;
}

struct Blades { Mono m[32]; };
constexpr Blades make_blades() {
    Blades B{};
    for (int A = 0; A < 32; ++A) {
        Mono M{};
        for (int r = 0; r < 4; ++r) { M.col[r] = r; M.ph[r] = 0; }
        for (int g = 0; g < 5; ++g)
            if ((A >> g) & 1) M = mono_mul(M, gen(g));
        B.m[A] = M;
    }
    return B;
}
constexpr Blades BL = make_blades();

// Forward table: matrix entry (row r, col c, rc=0:Re/1:Im) = sum of 4 signed blade coeffs.
struct FwdTab { int bl[4][4][2][4]; float sg[4][4][2][4]; };
constexpr FwdTab make_fwd() {
    FwdTab T{};
    int cnt[4][4][2] = {};
    for (int A = 0; A < 32; ++A)
        for (int r = 0; r < 4; ++r) {
            int c = BL.m[A].col[r], p = BL.m[A].ph[r];
            int rc = p & 1;
            int& n = cnt[r][c][rc];
            T.bl[r][c][rc][n] = A;
            T.sg[r][c][rc][n] = (p & 2) ? -1.f : 1.f;
            ++n;
        }
    return T;
}
constexpr FwdTab FT = make_fwd();

__device__ inline unsigned short f2bf(float f) {
    uint32_t u = __float_as_uint(f);
    u += 0x7FFFu + ((u >> 16) & 1u);
    return (unsigned short)(u >> 16);
}

// ---- kernel 1 (fused transforms) ----
// blocks [0,2048):    x[n,i,0..31] -> X̂ rows: Xb[(n*4+b)][i*8 + c*2 + rc]  (bf16)
// blocks [2048,2304): w[o,i,0..31] -> Ŵ real-embed: Wr[(o*8+ra*4+a)][i*8 + c*2 + rc]
__global__ __launch_bounds__(256) void xform_kernel(const float* __restrict__ x,
                                                    const float* __restrict__ w,
                                                    unsigned short* __restrict__ Xb,
                                                    unsigned short* __restrict__ Wr) {
    if (blockIdx.x < 2048) {
        int t = blockIdx.x * 256 + threadIdx.x;     // t = n*256 + i
        int i = t & 255, n = t >> 8;
        float v[32];
        const float4* xp = (const float4*)(x + (size_t)t * 32);
#pragma unroll
        for (int q = 0; q < 8; ++q) {
            float4 f = xp[q];
            v[q * 4 + 0] = f.x; v[q * 4 + 1] = f.y; v[q * 4 + 2] = f.z; v[q * 4 + 3] = f.w;
        }
#pragma unroll
        for (int b = 0; b < 4; ++b) {
            union { unsigned short s[8]; uint4 u; } r;
#pragma unroll
            for (int c = 0; c < 4; ++c)
#pragma unroll
                for (int rc = 0; rc < 2; ++rc) {
                    float s = 0.f;
#pragma unroll
                    for (int j = 0; j < 4; ++j)
                        s += FT.sg[c][b][rc][j] * v[FT.bl[c][b][rc][j]];
                    r.s[c * 2 + rc] = f2bf(s);
                }
            *((uint4*)(Xb + (size_t)(n * 4 + b) * 2048 + i * 8)) = r.u;
        }
    } else {
        int t = (blockIdx.x - 2048) * 256 + threadIdx.x;   // t = o*256 + i
        int i = t & 255, o = t >> 8;
        float v[32];
        const float4* wp = (const float4*)(w + (size_t)t * 32);
#pragma unroll
        for (int q = 0; q < 8; ++q) {
            float4 f = wp[q];
            v[q * 4 + 0] = f.x; v[q * 4 + 1] = f.y; v[q * 4 + 2] = f.z; v[q * 4 + 3] = f.w;
        }
        float Re[4][4], Im[4][4];
#pragma unroll
        for (int a = 0; a < 4; ++a)
#pragma unroll
            for (int c = 0; c < 4; ++c) {
                float sr = 0.f, si = 0.f;
#pragma unroll
                for (int j = 0; j < 4; ++j) {
                    sr += FT.sg[a][c][0][j] * v[FT.bl[a][c][0][j]];
                    si += FT.sg[a][c][1][j] * v[FT.bl[a][c][1][j]];
                }
                Re[a][c] = sr; Im[a][c] = si;
            }
#pragma unroll
        for (int ra = 0; ra < 2; ++ra)
#pragma unroll
            for (int a = 0; a < 4; ++a) {
                int m = o * 8 + ra * 4 + a;   // complete multivectors per 8-row group
                union { unsigned short s[8]; uint4 u; } r;
#pragma unroll
                for (int c = 0; c < 4; ++c) {
                    float v0 = ra == 0 ? Re[a][c] : Im[a][c];
                    float v1 = ra == 0 ? -Im[a][c] : Re[a][c];
                    r.s[c * 2 + 0] = f2bf(v0);
                    r.s[c * 2 + 1] = f2bf(v1);
                }
                *((uint4*)(Wr + (size_t)m * 2048 + i * 8)) = r.u;
            }
    }
}

// ---- kernel 2: fused GEMM + inverse transform + L2 normalize ----
// C_virtual[2048,8192] = Wr * Xb^T, never materialized: per ti-stripe the 32x128 fp32
// patch goes through LDS, gets inverse-transformed per 32-value group, normalized,
// and written straight to out[n,o,0..31].
__global__ __launch_bounds__(256) void gemm_kernel(const unsigned short* __restrict__ A,
                                                   const unsigned short* __restrict__ B,
                                                   float* __restrict__ out) {
    const int K = 2048;
    __shared__ alignas(16) unsigned short SMEM[2 * 128 * 32];   // 16 KB
    unsigned short* As = SMEM;
    unsigned short* Bs = SMEM + 128 * 32;
    float* scr = (float*)SMEM;                                  // 32 x 128 fp32 (epilogue)

    int tid = threadIdx.x;
    int wid = tid >> 6, lane = tid & 63;
    int row0 = blockIdx.y * 128;   // M panels (16): o-groups
    int col0 = blockIdx.x * 128;   // N panels (64): n-groups
    int wr = (wid >> 1) * 64, wc = (wid & 1) * 64;
    int lm = lane & 15, quad = lane >> 4;

    f32x4 acc[4][4];
#pragma unroll
    for (int ti = 0; ti < 4; ++ti)
#pragma unroll
        for (int tj = 0; tj < 4; ++tj)
            acc[ti][tj] = (f32x4){0.f, 0.f, 0.f, 0.f};

    for (int k0 = 0; k0 < K; k0 += 32) {
#pragma unroll
        for (int p = 0; p < 2; ++p) {
            int c = p * 256 + tid;
            int m = c >> 2;
            int off = (c & 3) * 8;
            const unsigned short* ga = A + (size_t)(row0 + m) * K + k0 + off;
            const unsigned short* gb = B + (size_t)(col0 + m) * K + k0 + off;
            unsigned short* la = &As[(size_t)(p * 256 + wid * 64) * 8];
            unsigned short* lb = &Bs[(size_t)(p * 256 + wid * 64) * 8];
            __builtin_amdgcn_global_load_lds((const AS1 void*)ga, (AS3 void*)la, 16, 0, 0);
            __builtin_amdgcn_global_load_lds((const AS1 void*)gb, (AS3 void*)lb, 16, 0, 0);
        }
        __syncthreads();

        bf16x8 af[4], bfr[4];
#pragma unroll
        for (int ti = 0; ti < 4; ++ti)
            af[ti] = *(const bf16x8*)&As[(wr + ti * 16 + lm) * 32 + quad * 8];
#pragma unroll
        for (int tj = 0; tj < 4; ++tj)
            bfr[tj] = *(const bf16x8*)&Bs[(wc + tj * 16 + lm) * 32 + quad * 8];
#pragma unroll
        for (int ti = 0; ti < 4; ++ti)
#pragma unroll
            for (int tj = 0; tj < 4; ++tj)
                acc[ti][tj] = __builtin_amdgcn_mfma_f32_16x16x32_bf16(af[ti], bfr[tj],
                                                                      acc[ti][tj], 0, 0, 0);
        __syncthreads();
    }

    // ---- fused epilogue, one 32-row stripe (both wave bands at this ti) at a time ----
    int band = wr >> 6;   // 0 or 1
#pragma unroll 1
    for (int ti = 0; ti < 4; ++ti) {
        __syncthreads();
        // stage this stripe's acc patch: scr[band*16 + quad*4 + r][wc + tj*16 + lm]
#pragma unroll
        for (int tj = 0; tj < 4; ++tj)
#pragma unroll
            for (int r = 0; r < 4; ++r)
                scr[(band * 16 + quad * 4 + r) * 128 + (wc + tj * 16 + lm)] = acc[ti][tj][r];
        __syncthreads();

        if (tid < 128) {
            int n_l = tid & 31, og = tid >> 5;     // 4 o-groups x 32 n's in this stripe
            int o_local = (og >> 1) * 8 + ti * 2 + (og & 1);
            int srow0 = (og >> 1) * 16 + (og & 1) * 8;
            float V[32];   // V[ra*16 + a*4 + b]
#pragma unroll
            for (int u = 0; u < 8; ++u) {          // u = ra*4 + a
                float4 f = *(const float4*)&scr[(srow0 + u) * 128 + n_l * 4];
                int vi = (u >> 2) * 16 + (u & 3) * 4;
                V[vi + 0] = f.x; V[vi + 1] = f.y; V[vi + 2] = f.z; V[vi + 3] = f.w;
            }
            float xa[32];
            float ss = 0.f;
#pragma unroll
            for (int Ab = 0; Ab < 32; ++Ab) {
                float s = 0.f;
#pragma unroll
                for (int a = 0; a < 4; ++a) {
                    const int c = BL.m[Ab].col[a];
                    const int p = BL.m[Ab].ph[a];
                    float vv = V[(p & 1) * 16 + a * 4 + c];
                    s += (p & 2) ? -vv : vv;
                }
                s *= 0.25f;
                xa[Ab] = s;
                ss += s * s;
            }
            float inv = rsqrtf(ss + 1e-6f);
            int n = (col0 >> 2) + n_l;
            int o = (row0 >> 3) + o_local;
            float4* op = (float4*)(out + ((size_t)n * 256 + o) * 32);
#pragma unroll
            for (int q = 0; q < 8; ++q) {
                float4 f;
                f.x = xa[q * 4 + 0] * inv; f.y = xa[q * 4 + 1] * inv;
                f.z = xa[q * 4 + 2] * inv; f.w = xa[q * 4 + 3] * inv;
                op[q] = f;
            }
        }
    }
}

extern "C" void kernel_launch(void* const* d_in, const int* in_sizes, int n_in,
                              void* d_out, int out_size, void* d_ws, size_t ws_size,
                              hipStream_t stream) {
    const float* x = (const float*)d_in[0];   // [4,512,256,32]
    const float* w = (const float*)d_in[1];   // [256,256,32]
    float* out = (float*)d_out;               // [4,512,256,32]

    unsigned short* Wr = (unsigned short*)d_ws;                             //  8,388,608 B
    unsigned short* Xb = (unsigned short*)((char*)d_ws + 8388608);          // 33,554,432 B

    hipLaunchKernelGGL(xform_kernel, dim3(2304),   dim3(256), 0, stream, x, w, Xb, Wr);
    hipLaunchKernelGGL(gemm_kernel,  dim3(64, 16), dim3(256), 0, stream, Wr, Xb, out);
}

// Round 5
// 231.072 us; speedup vs baseline: 3.0347x; 3.0347x over previous
//
#include <hip/hip_runtime.h>
#include <stdint.h>

#define AS1 __attribute__((address_space(1)))
#define AS3 __attribute__((address_space(3)))

typedef __attribute__((ext_vector_type(8))) short bf16x8;
typedef __attribute__((ext_vector_type(4))) float f32x4;

// ================= Cl(4,1) ~= M4(C) isomorphism, built at compile time =================
// Generators (monomial 4x4 complex, entries i^ph):
//  E0=s1(x)I, E1=s2(x)I, E2=s3(x)s1, E3=s3(x)s2 (square +1); E4=i*s3(x)s3 (square -1).
// Blade A (5-bit mask) -> M_A = product of E_b over set bits, ascending. Each M_A is
// monomial: M_A[r, col[r]] = i^ph[r].

struct Mono { int col[4]; int ph[4]; };

constexpr Mono mono_mul(Mono A, Mono B) {
    Mono R{};
    for (int r = 0; r < 4; ++r) {
        int k = A.col[r];
        R.col[r] = B.col[k];
        R.ph[r] = (A.ph[r] + B.ph[k]) & 3;
    }
    return R;
}

constexpr Mono gen(int g) {
    Mono E{};
    for (int r = 0; r < 4; ++r) {
        int r1 = (r >> 1) & 1, r0 = r & 1;
        if (g == 0)      { E.col[r] = r ^ 2; E.ph[r] = 0; }
        else if (g == 1) { E.col[r] = r ^ 2; E.ph[r] = r1 ? 1 : 3; }
        else if (g == 2) { E.col[r] = r ^ 1; E.ph[r] = r1 ? 2 : 0; }
        else if (g == 3) { E.col[r] = r ^ 1; E.ph[r] = ((r1 ? 2 : 0) + (r0 ? 1 : 3)) & 3; }
        else             { E.col[r] = r;     E.ph[r] = (1 + (r1 ? 2 : 0) + (r0 ? 2 : 0)) & 3; }
    }
    return E;
}

struct Blades { Mono m[32]; };
constexpr Blades make_blades() {
    Blades B{};
    for (int A = 0; A < 32; ++A) {
        Mono M{};
        for (int r = 0; r < 4; ++r) { M.col[r] = r; M.ph[r] = 0; }
        for (int g = 0; g < 5; ++g)
            if ((A >> g) & 1) M = mono_mul(M, gen(g));
        B.m[A] = M;
    }
    return B;
}
constexpr Blades BL = make_blades();

// Forward table: matrix entry (row r, col c, rc=0:Re/1:Im) = sum of 4 signed blade coeffs.
struct FwdTab { int bl[4][4][2][4]; float sg[4][4][2][4]; };
constexpr FwdTab make_fwd() {
    FwdTab T{};
    int cnt[4][4][2] = {};
    for (int A = 0; A < 32; ++A)
        for (int r = 0; r < 4; ++r) {
            int c = BL.m[A].col[r], p = BL.m[A].ph[r];
            int rc = p & 1;
            int& n = cnt[r][c][rc];
            T.bl[r][c][rc][n] = A;
            T.sg[r][c][rc][n] = (p & 2) ? -1.f : 1.f;
            ++n;
        }
    return T;
}
constexpr FwdTab FT = make_fwd();

__device__ inline unsigned short f2bf(float f) {
    uint32_t u = __float_as_uint(f);
    u += 0x7FFFu + ((u >> 16) & 1u);
    return (unsigned short)(u >> 16);
}

// ---- kernel 1 (fused transforms) ----
// blocks [0,2048):    x[n,i,0..31] -> X̂ rows: Xb[(n*4+b)][i*8 + c*2 + rc]  (bf16)
// blocks [2048,2304): w[o,i,0..31] -> Ŵ real-embed: Wr[(o*8+ra*4+a)][i*8 + c*2 + rc]
__global__ __launch_bounds__(256) void xform_kernel(const float* __restrict__ x,
                                                    const float* __restrict__ w,
                                                    unsigned short* __restrict__ Xb,
                                                    unsigned short* __restrict__ Wr) {
    if (blockIdx.x < 2048) {
        int t = blockIdx.x * 256 + threadIdx.x;     // t = n*256 + i
        int i = t & 255, n = t >> 8;
        float v[32];
        const float4* xp = (const float4*)(x + (size_t)t * 32);
#pragma unroll
        for (int q = 0; q < 8; ++q) {
            float4 f = xp[q];
            v[q * 4 + 0] = f.x; v[q * 4 + 1] = f.y; v[q * 4 + 2] = f.z; v[q * 4 + 3] = f.w;
        }
#pragma unroll
        for (int b = 0; b < 4; ++b) {
            union { unsigned short s[8]; uint4 u; } r;
#pragma unroll
            for (int c = 0; c < 4; ++c)
#pragma unroll
                for (int rc = 0; rc < 2; ++rc) {
                    float s = 0.f;
#pragma unroll
                    for (int j = 0; j < 4; ++j)
                        s += FT.sg[c][b][rc][j] * v[FT.bl[c][b][rc][j]];
                    r.s[c * 2 + rc] = f2bf(s);
                }
            *((uint4*)(Xb + (size_t)(n * 4 + b) * 2048 + i * 8)) = r.u;
        }
    } else {
        int t = (blockIdx.x - 2048) * 256 + threadIdx.x;   // t = o*256 + i
        int i = t & 255, o = t >> 8;
        float v[32];
        const float4* wp = (const float4*)(w + (size_t)t * 32);
#pragma unroll
        for (int q = 0; q < 8; ++q) {
            float4 f = wp[q];
            v[q * 4 + 0] = f.x; v[q * 4 + 1] = f.y; v[q * 4 + 2] = f.z; v[q * 4 + 3] = f.w;
        }
        float Re[4][4], Im[4][4];
#pragma unroll
        for (int a = 0; a < 4; ++a)
#pragma unroll
            for (int c = 0; c < 4; ++c) {
                float sr = 0.f, si = 0.f;
#pragma unroll
                for (int j = 0; j < 4; ++j) {
                    sr += FT.sg[a][c][0][j] * v[FT.bl[a][c][0][j]];
                    si += FT.sg[a][c][1][j] * v[FT.bl[a][c][1][j]];
                }
                Re[a][c] = sr; Im[a][c] = si;
            }
#pragma unroll
        for (int ra = 0; ra < 2; ++ra)
#pragma unroll
            for (int a = 0; a < 4; ++a) {
                int m = o * 8 + ra * 4 + a;   // complete multivectors per 8-row group
                union { unsigned short s[8]; uint4 u; } r;
#pragma unroll
                for (int c = 0; c < 4; ++c) {
                    float v0 = ra == 0 ? Re[a][c] : Im[a][c];
                    float v1 = ra == 0 ? -Im[a][c] : Re[a][c];
                    r.s[c * 2 + 0] = f2bf(v0);
                    r.s[c * 2 + 1] = f2bf(v1);
                }
                *((uint4*)(Wr + (size_t)m * 2048 + i * 8)) = r.u;
            }
    }
}

// ---- kernel 2: fused GEMM + inverse transform + L2 normalize ----
// C_virtual[2048,8192] = Wr * Xb^T, never materialized: per ti-stripe the 32x128 fp32
// patch goes through LDS, gets inverse-transformed per 32-value group, normalized,
// and written straight to out[n,o,0..31].
// NOTE: the epilogue ti-loop MUST be fully unrolled — a runtime index into acc[][]
// demotes the accumulator array to scratch for the whole kernel (R4: 3.5 GB of
// scratch write traffic, 5x regression).
__global__ __launch_bounds__(256) void gemm_kernel(const unsigned short* __restrict__ A,
                                                   const unsigned short* __restrict__ B,
                                                   float* __restrict__ out) {
    const int K = 2048;
    __shared__ alignas(16) unsigned short SMEM[2 * 128 * 32];   // 16 KB
    unsigned short* As = SMEM;
    unsigned short* Bs = SMEM + 128 * 32;
    float* scr = (float*)SMEM;                                  // 32 x 128 fp32 (epilogue)

    int tid = threadIdx.x;
    int wid = tid >> 6, lane = tid & 63;
    int row0 = blockIdx.y * 128;   // M panels (16): o-groups
    int col0 = blockIdx.x * 128;   // N panels (64): n-groups
    int wr = (wid >> 1) * 64, wc = (wid & 1) * 64;
    int lm = lane & 15, quad = lane >> 4;

    f32x4 acc[4][4];
#pragma unroll
    for (int ti = 0; ti < 4; ++ti)
#pragma unroll
        for (int tj = 0; tj < 4; ++tj)
            acc[ti][tj] = (f32x4){0.f, 0.f, 0.f, 0.f};

    for (int k0 = 0; k0 < K; k0 += 32) {
#pragma unroll
        for (int p = 0; p < 2; ++p) {
            int c = p * 256 + tid;
            int m = c >> 2;
            int off = (c & 3) * 8;
            const unsigned short* ga = A + (size_t)(row0 + m) * K + k0 + off;
            const unsigned short* gb = B + (size_t)(col0 + m) * K + k0 + off;
            unsigned short* la = &As[(size_t)(p * 256 + wid * 64) * 8];
            unsigned short* lb = &Bs[(size_t)(p * 256 + wid * 64) * 8];
            __builtin_amdgcn_global_load_lds((const AS1 void*)ga, (AS3 void*)la, 16, 0, 0);
            __builtin_amdgcn_global_load_lds((const AS1 void*)gb, (AS3 void*)lb, 16, 0, 0);
        }
        __syncthreads();

        bf16x8 af[4], bfr[4];
#pragma unroll
        for (int ti = 0; ti < 4; ++ti)
            af[ti] = *(const bf16x8*)&As[(wr + ti * 16 + lm) * 32 + quad * 8];
#pragma unroll
        for (int tj = 0; tj < 4; ++tj)
            bfr[tj] = *(const bf16x8*)&Bs[(wc + tj * 16 + lm) * 32 + quad * 8];
#pragma unroll
        for (int ti = 0; ti < 4; ++ti)
#pragma unroll
            for (int tj = 0; tj < 4; ++tj)
                acc[ti][tj] = __builtin_amdgcn_mfma_f32_16x16x32_bf16(af[ti], bfr[tj],
                                                                      acc[ti][tj], 0, 0, 0);
        __syncthreads();
    }

    // ---- fused epilogue, one 32-row stripe (both wave bands at this ti) at a time ----
    int band = wr >> 6;   // 0 or 1
#pragma unroll
    for (int ti = 0; ti < 4; ++ti) {
        __syncthreads();
        // stage this stripe's acc patch: scr[band*16 + quad*4 + r][wc + tj*16 + lm]
#pragma unroll
        for (int tj = 0; tj < 4; ++tj)
#pragma unroll
            for (int r = 0; r < 4; ++r)
                scr[(band * 16 + quad * 4 + r) * 128 + (wc + tj * 16 + lm)] = acc[ti][tj][r];
        __syncthreads();

        if (tid < 128) {
            int n_l = tid & 31, og = tid >> 5;     // 4 o-groups x 32 n's in this stripe
            int o_local = (og >> 1) * 8 + ti * 2 + (og & 1);
            int srow0 = (og >> 1) * 16 + (og & 1) * 8;
            float V[32];   // V[ra*16 + a*4 + b]
#pragma unroll
            for (int u = 0; u < 8; ++u) {          // u = ra*4 + a
                float4 f = *(const float4*)&scr[(srow0 + u) * 128 + n_l * 4];
                int vi = (u >> 2) * 16 + (u & 3) * 4;
                V[vi + 0] = f.x; V[vi + 1] = f.y; V[vi + 2] = f.z; V[vi + 3] = f.w;
            }
            float xa[32];
            float ss = 0.f;
#pragma unroll
            for (int Ab = 0; Ab < 32; ++Ab) {
                float s = 0.f;
#pragma unroll
                for (int a = 0; a < 4; ++a) {
                    const int c = BL.m[Ab].col[a];
                    const int p = BL.m[Ab].ph[a];
                    float vv = V[(p & 1) * 16 + a * 4 + c];
                    s += (p & 2) ? -vv : vv;
                }
                s *= 0.25f;
                xa[Ab] = s;
                ss += s * s;
            }
            float inv = rsqrtf(ss + 1e-6f);
            int n = (col0 >> 2) + n_l;
            int o = (row0 >> 3) + o_local;
            float4* op = (float4*)(out + ((size_t)n * 256 + o) * 32);
#pragma unroll
            for (int q = 0; q < 8; ++q) {
                float4 f;
                f.x = xa[q * 4 + 0] * inv; f.y = xa[q * 4 + 1] * inv;
                f.z = xa[q * 4 + 2] * inv; f.w = xa[q * 4 + 3] * inv;
                op[q] = f;
            }
        }
    }
}

extern "C" void kernel_launch(void* const* d_in, const int* in_sizes, int n_in,
                              void* d_out, int out_size, void* d_ws, size_t ws_size,
                              hipStream_t stream) {
    const float* x = (const float*)d_in[0];   // [4,512,256,32]
    const float* w = (const float*)d_in[1];   // [256,256,32]
    float* out = (float*)d_out;               // [4,512,256,32]

    unsigned short* Wr = (unsigned short*)d_ws;                             //  8,388,608 B
    unsigned short* Xb = (unsigned short*)((char*)d_ws + 8388608);          // 33,554,432 B

    hipLaunchKernelGGL(xform_kernel, dim3(2304),   dim3(256), 0, stream, x, w, Xb, Wr);
    hipLaunchKernelGGL(gemm_kernel,  dim3(64, 16), dim3(256), 0, stream, Wr, Xb, out);
}